// Round 11
// baseline (784.165 us; speedup 1.0000x reference)
//
#include <hip/hip_runtime.h>
#include <math.h>
#include <stdint.h>

#define HP 256
#define PTS 8                 // points per workgroup (two groups of 4)
#define ROWS 64               // 2 groups x (4 points x 8 channels)
#define PSTR 264              // halves per A row (dw-stride 132 == 4 mod 32 -> 0-conflict, measured)
#define NLAYER 6
#define WT_ELEMS (6*256*256)  // fp16 transposed weights

typedef _Float16 half8 __attribute__((ext_vector_type(8)));
typedef float  float16v __attribute__((ext_vector_type(16)));

// f32 extras section (float offsets; section starts at byte WT_ELEMS*2)
#define C_WI 0                // [3][256]
#define C_BI 768              // [256]
#define C_BH 1024             // [6][256]
#define C_WO 2560             // [256][4]
#define C_TOT 3584

__device__ __forceinline__ float fast_tanh(float x) {
    float e = __expf(2.0f * x);
    return 1.0f - __fdividef(2.0f, e + 1.0f);
}

__device__ __forceinline__ float16v zero16() {
    float16v z;
    #pragma unroll
    for (int i = 0; i < 16; ++i) z[i] = 0.0f;
    return z;
}

// A-row for (point P in 0..7, channel c in 0..7). Group g = P>>2 -> rows 32g..32g+31.
// Within the 32x32 MFMA C-layout (row=(reg&3)+8*(reg>>2)+4*hi5) each lane's reg
// quads 2pp / 2pp+1 hold ch0-3 / ch4-7 of local point 2pp+hi5 -> shuffle-free epilogue.
__device__ __forceinline__ int arow(int P, int c) {
    return 32*(P >> 2) + 16*((P >> 1) & 1) + 4*(P & 1) + 8*(c >> 2) + (c & 3);
}

#define MFMA16(A,B,Cc) __builtin_amdgcn_mfma_f32_32x32x16_f16((A),(B),(Cc),0,0,0)

// ---------------- prep: transpose weights to fp16 ----------------
__global__ void prep_kernel(const float* __restrict__ W_in, const float* __restrict__ b_in,
                            const float* __restrict__ W_h,  const float* __restrict__ b_h,
                            const float* __restrict__ W_out, void* __restrict__ wsv)
{
    _Float16* wt = (_Float16*)wsv;
    float* cf = (float*)((char*)wsv + (size_t)WT_ELEMS * 2);

    int i0 = blockIdx.x * blockDim.x + threadIdx.x;
    int stride = gridDim.x * blockDim.x;
    for (int i = i0; i < WT_ELEMS; i += stride) {
        int l = i >> 16, n = (i >> 8) & 255, k = i & 255;
        float w = (n < 250 && k < 250) ? W_h[(l*250 + k)*250 + n] : 0.0f;  // Wt[l][n][k]
        wt[i] = (_Float16)w;
    }
    for (int i = i0; i < C_TOT; i += stride) {
        float v = 0.0f;
        if (i < C_BI) { int r = i >> 8, j = i & 255; if (j < 250) v = W_in[r*250 + j]; }
        else if (i < C_BH) { int j = i - C_BI; if (j < 250) v = b_in[j]; }
        else if (i < C_WO) { int idx = i - C_BH; int l = idx >> 8, j = idx & 255; if (j < 250) v = b_h[l*250 + j]; }
        else { int idx = i - C_WO; int k = idx >> 2, o = idx & 3; if (k < 250) v = W_out[k*4 + o]; }
        cf[i] = v;
    }
}

// PHASE: K-loop for group GK layer LK (fills M0/M1 = 2 col-subtiles) interleaved
// 4:1 with epilogue for group GE layer LE (consumes E0/E1, writes GE's A rows).
// DOK/DOE are 0/1 literals; dead branches fold at -O3.
#define PHASE(DOK, GK, LK, M0, M1, DOE, GE, LE, E0, E1) do {                   \
  const _Float16* ph0_ = wt; const _Float16* ph1_ = wt;                        \
  half8 b0_{}, b1_{}, nb0_{}, nb1_{}, a0_{};                                   \
  int abase_ = 0;                                                              \
  if (DOK) {                                                                   \
    ph0_ = wt + (((size_t)(LK)) << 16) + (size_t)n0 * 256 + 8*hi5;             \
    ph1_ = ph0_ + 32*256;                                                      \
    b0_  = *(const half8*)(ph0_);      b1_  = *(const half8*)(ph1_);           \
    nb0_ = *(const half8*)(ph0_ + 16); nb1_ = *(const half8*)(ph1_ + 16);      \
    M0 = zero16(); M1 = zero16();                                              \
    abase_ = (32*(GK) + lo5) * PSTR + 8*hi5;                                   \
    a0_ = *(const half8*)&Ah[abase_];                                          \
  }                                                                            \
  float bb0_ = 0.f, bb1_ = 0.f, cc_ = 0.f;                                     \
  if (DOE) {                                                                   \
    bb0_ = cf[C_BH + ((LE) << 8) + n0];                                        \
    bb1_ = cf[C_BH + ((LE) << 8) + n0 + 32];                                   \
    cc_  = 10.0f * act[(LE) + 1];                                              \
  }                                                                            \
  _Pragma("unroll")                                                            \
  for (int ch_ = 0; ch_ < 4; ++ch_) {                                          \
    if (DOK) {                                                                 \
      _Pragma("unroll")                                                        \
      for (int u_ = 0; u_ < 4; ++u_) {                                         \
        const int s_ = 4*ch_ + u_;                                             \
        half8 p0_{}, p1_{}, na0_{};                                            \
        if (s_ < 14) {                                                         \
          p0_ = *(const half8*)(ph0_ + 16*(s_ + 2));                           \
          p1_ = *(const half8*)(ph1_ + 16*(s_ + 2));                           \
        }                                                                      \
        if (s_ < 15) na0_ = *(const half8*)&Ah[abase_ + 16*(s_ + 1)];          \
        M0 = MFMA16(a0_, b0_, M0);                                             \
        M1 = MFMA16(a0_, b1_, M1);                                             \
        a0_ = na0_;                                                            \
        b0_ = nb0_; b1_ = nb1_;                                                \
        nb0_ = p0_; nb1_ = p1_;                                                \
      }                                                                        \
    }                                                                          \
    if (DOE) {                                                                 \
      const int t_ = ch_ >> 1, pp_ = ch_ & 1;                                  \
      float16v mv_ = t_ ? (E1) : (E0);                                         \
      float z_   = mv_[8*pp_+0] + (t_ ? bb1_ : bb0_);                          \
      float zx_  = mv_[8*pp_+1];                                               \
      float zy_  = mv_[8*pp_+2];                                               \
      float zt_  = mv_[8*pp_+3];                                               \
      float zxx_ = mv_[8*pp_+4];                                               \
      float zyy_ = mv_[8*pp_+5];                                               \
      float zxy_ = mv_[8*pp_+6];                                               \
      float y_   = fast_tanh(cc_ * z_);                                        \
      float sh_  = 1.0f - y_*y_;                                               \
      float cs_  = cc_ * sh_;                                                  \
      float m2_  = -2.0f * cc_ * cs_ * y_;                                     \
      const int ncol_ = 64*qtr + 32*t_ + lo5;                                  \
      const int r0_ = (32*(GE) + 16*pp_ + 4*hi5) * PSTR + ncol_;               \
      Ah[r0_ + 0*PSTR] = (_Float16)y_;                                         \
      Ah[r0_ + 1*PSTR] = (_Float16)(cs_*zx_);                                  \
      Ah[r0_ + 2*PSTR] = (_Float16)(cs_*zy_);                                  \
      Ah[r0_ + 3*PSTR] = (_Float16)(cs_*zt_);                                  \
      const int r1_ = r0_ + 8*PSTR;                                            \
      Ah[r1_ + 0*PSTR] = (_Float16)(cs_*zxx_ + m2_*zx_*zx_);                   \
      Ah[r1_ + 1*PSTR] = (_Float16)(cs_*zyy_ + m2_*zy_*zy_);                   \
      Ah[r1_ + 2*PSTR] = (_Float16)(cs_*zxy_ + m2_*zx_*zy_);                   \
      Ah[r1_ + 3*PSTR] = (_Float16)0.0f;                                       \
    }                                                                          \
  }                                                                            \
} while (0)

// ---------------- fused PINN kernel ----------------
// 256 threads = 4 waves; wave qtr owns cols 64*qtr..+63 (2 col-subtiles).
// Two-group pipeline: each phase = one group's 32-MFMA K-loop interleaved with
// the other group's epilogue, so MFMA is in flight during epilogue VALU.
__launch_bounds__(256, 3)
__global__ void pinn_mfma(const float* __restrict__ xg, const float* __restrict__ yg,
                          const float* __restrict__ tg, const void* __restrict__ wsv,
                          const float* __restrict__ b_out, const float* __restrict__ act,
                          float* __restrict__ out, int N)
{
    __shared__ _Float16 Ah[ROWS * PSTR];
    __shared__ float zo[PTS][28];

    const _Float16* __restrict__ wt = (const _Float16*)wsv;
    const float* __restrict__ cf = (const float*)((const char*)wsv + (size_t)WT_ELEMS * 2);

    const int tid  = threadIdx.x;
    const int lane = tid & 63;
    const int qtr  = tid >> 6;        // col quarter: 64*qtr
    const int lo5  = lane & 31;
    const int hi5  = lane >> 5;
    const int n0   = 64*qtr + lo5;

    // ---------- input layer jet: thread j = tid handles neuron j for all 8 points ----------
    {
        int j = tid;
        float wi0 = cf[C_WI + j], wi1 = cf[C_WI + 256 + j], wi2 = cf[C_WI + 512 + j];
        float biv = cf[C_BI + j];
        float c0 = 10.0f * act[0];
        #pragma unroll
        for (int p = 0; p < PTS; ++p) {
            int gp = blockIdx.x * PTS + p;
            gp = gp < N ? gp : N - 1;
            float px = xg[gp], py = yg[gp], pt = tg[gp];
            float z = px*wi0 + py*wi1 + pt*wi2 + biv;
            float y = fast_tanh(c0 * z);
            float s = 1.0f - y*y;
            float cs = c0 * s;
            float m2 = -2.0f * c0 * cs * y;
            float o[8];
            o[0] = y;           o[1] = cs*wi0;      o[2] = cs*wi1;      o[3] = cs*wi2;
            o[4] = m2*wi0*wi0;  o[5] = m2*wi1*wi1;  o[6] = m2*wi0*wi1;  o[7] = 0.0f;
            #pragma unroll
            for (int c = 0; c < 8; ++c)
                Ah[arow(p, c)*PSTR + j] = (_Float16)o[c];
        }
    }

    float16v A0, A1;   // group 0 accumulators (col-subtiles 0,1)
    float16v B0, B1;   // group 1 accumulators

    __syncthreads();
    // P0: K(g0, L0) only
    PHASE(1, 0, 0, A0, A1,  0, 0, 0, A0, A1);

    for (int L = 0; L < NLAYER; ++L) {
        __syncthreads();
        // K(g1, L) + E(g0, L)
        PHASE(1, 1, L, B0, B1,  1, 0, L, A0, A1);
        __syncthreads();
        if (L + 1 < NLAYER) {
            // K(g0, L+1) + E(g1, L)
            PHASE(1, 0, L+1, A0, A1,  1, 1, L, B0, B1);
        } else {
            // tail: E(g1, L) only
            PHASE(0, 0, 0, A0, A1,  1, 1, L, B0, B1);
        }
    }

    // ---------- output layer: 28 dots per point ----------
    __syncthreads();
    if (tid < PTS * 28) {
        int p = tid / 28, idx = tid % 28;
        int c = idx >> 2, o = idx & 3;
        const _Float16* rh = &Ah[arow(p, c) * PSTR];
        float s = 0.0f;
        for (int k = 0; k < HP; ++k)
            s += (float)rh[k] * cf[C_WO + 4*k + o];
        zo[p][idx] = s;
    }
    __syncthreads();

    // ---------- heads + PDE residuals ----------
    if (tid < PTS) {
        int gp = blockIdx.x * PTS + tid;
        if (gp < N) {
            float zc[7][4];
            #pragma unroll
            for (int c = 0; c < 7; ++c)
                #pragma unroll
                for (int o = 0; o < 4; ++o)
                    zc[c][o] = zo[tid][c*4 + o] + (c == 0 ? b_out[o] : 0.0f);

            float u  = zc[0][0], vv = zc[0][1];
            float u_x = zc[1][0], u_y = zc[2][0], u_t = zc[3][0];
            float u_xx = zc[4][0], u_yy = zc[5][0];
            float v_x = zc[1][1], v_y = zc[2][1], v_t = zc[3][1];
            float v_xx = zc[4][1], v_yy = zc[5][1];

            float ep  = expf(zc[0][2]);
            float p_x = ep * zc[1][2], p_y = ep * zc[2][2];

            float a   = 1.0f / (1.0f + expf(-zc[0][3]));
            float sp  = a * (1.0f - a);
            float spp = sp * (1.0f - 2.0f*a);
            float z1a = zc[1][3], z2a = zc[2][3];
            float a_x = sp * z1a, a_y = sp * z2a, a_t = sp * zc[3][3];
            float a_xx = spp*z1a*z1a + sp*zc[4][3];
            float a_yy = spp*z2a*z2a + sp*zc[5][3];
            float a_xy = spp*z1a*z2a + sp*zc[6][3];

            float mu_x = -9.0f*a_x, mu_y = -9.0f*a_y;
            float mu   = 10.0f - 9.0f*a;
            float rr   = 1.0f - 0.9f*a;
            float g  = sqrtf(a_x*a_x + a_y*a_y + 2.220446049250313e-16f);
            float g3 = g*g*g;
            float curv = -((a_xx + a_yy)/g
                         - (a_x*a_x*a_xx + a_y*a_y*a_yy + 2.0f*a_x*a_y*a_xy)/g3);
            float one_Re   = mu   * 0.002f;
            float one_Re_x = mu_x * 0.002f;
            float one_Re_y = mu_y * 0.002f;

            float PDE_m = u_x + v_y;
            float PDE_a = a_t + u*a_x + vv*a_y;
            float PDE_u = (u_t + u*u_x + vv*u_y)*rr + p_x - 0.049f*curv*a_x
                        - one_Re*(u_xx + u_yy) - 2.0f*one_Re_x*u_x - one_Re_y*(u_y + v_x);
            float PDE_v = (v_t + u*v_x + vv*v_y)*rr + p_y - 0.049f*curv*a_y
                        - one_Re*(v_xx + v_yy) - rr*0.49f
                        - 2.0f*one_Re_y*v_y - one_Re_x*(u_y + v_x);

            out[0*N + gp] = PDE_m;
            out[1*N + gp] = PDE_u;
            out[2*N + gp] = PDE_v;
            out[3*N + gp] = PDE_a;
        }
    }
}

extern "C" void kernel_launch(void* const* d_in, const int* in_sizes, int n_in,
                              void* d_out, int out_size, void* d_ws, size_t ws_size,
                              hipStream_t stream)
{
    const float* x     = (const float*)d_in[0];
    const float* y     = (const float*)d_in[1];
    const float* t     = (const float*)d_in[2];
    const float* W_in  = (const float*)d_in[3];
    const float* b_in  = (const float*)d_in[4];
    const float* W_h   = (const float*)d_in[5];
    const float* b_h   = (const float*)d_in[6];
    const float* W_out = (const float*)d_in[7];
    const float* b_out = (const float*)d_in[8];
    const float* act   = (const float*)d_in[9];
    float* out = (float*)d_out;
    int N = in_sizes[0];

    hipLaunchKernelGGL(prep_kernel, dim3(512), dim3(256), 0, stream,
                       W_in, b_in, W_h, b_h, W_out, d_ws);
    int nb = (N + PTS - 1) / PTS;
    hipLaunchKernelGGL(pinn_mfma, dim3(nb), dim3(256), 0, stream,
                       x, y, t, d_ws, b_out, act, out, N);
}

// Round 12
// 457.404 us; speedup vs baseline: 1.7144x; 1.7144x over previous
//
#include <hip/hip_runtime.h>
#include <math.h>
#include <stdint.h>

#define HP 256
#define PTS 8                 // points per workgroup
#define ROWS 64               // 8 points x 8 channels (ch7 dummy)
#define PSTR 264              // halves per A row (dw-stride 132 == 4 mod 32 -> 0-conflict, measured)
#define NLAYER 6
#define WT_ELEMS (6*256*256)  // fp16 transposed weights

typedef _Float16 half8 __attribute__((ext_vector_type(8)));
typedef float  float16v __attribute__((ext_vector_type(16)));

// f32 extras section (float offsets; section starts at byte WT_ELEMS*2)
#define C_WI 0                // [3][256]
#define C_BI 768              // [256]
#define C_BH 1024             // [6][256]
#define C_WO 2560             // [256][4]
#define C_TOT 3584

__device__ __forceinline__ float fast_tanh(float x) {
    float e = __expf(2.0f * x);
    return 1.0f - __fdividef(2.0f, e + 1.0f);
}

__device__ __forceinline__ float16v zero16() {
    float16v z;
    #pragma unroll
    for (int i = 0; i < 16; ++i) z[i] = 0.0f;
    return z;
}

// A-row for (point P in 0..7, channel c in 0..7). Permuted so that in the
// 32x32 MFMA C-layout (row=(reg&3)+8*(reg>>2)+4*hi5) each lane's reg quads
// 2pp / 2pp+1 hold ch0-3 / ch4-7 of point 2pp+hi5 (per 32-row tile) ->
// shuffle-free, divergence-free epilogue. K-loop is row-perm invariant.
__device__ __forceinline__ int arow(int P, int c) {
    return 32*(P >> 2) + 16*((P >> 1) & 1) + 4*(P & 1) + 8*(c >> 2) + (c & 3);
}

#define MFMA16(A,B,Cc) __builtin_amdgcn_mfma_f32_32x32x16_f16((A),(B),(Cc),0,0,0)

// ---------------- prep: transpose weights to fp16 ----------------
__global__ void prep_kernel(const float* __restrict__ W_in, const float* __restrict__ b_in,
                            const float* __restrict__ W_h,  const float* __restrict__ b_h,
                            const float* __restrict__ W_out, void* __restrict__ wsv)
{
    _Float16* wt = (_Float16*)wsv;
    float* cf = (float*)((char*)wsv + (size_t)WT_ELEMS * 2);

    int i0 = blockIdx.x * blockDim.x + threadIdx.x;
    int stride = gridDim.x * blockDim.x;
    for (int i = i0; i < WT_ELEMS; i += stride) {
        int l = i >> 16, n = (i >> 8) & 255, k = i & 255;
        float w = (n < 250 && k < 250) ? W_h[(l*250 + k)*250 + n] : 0.0f;  // Wt[l][n][k]
        wt[i] = (_Float16)w;
    }
    for (int i = i0; i < C_TOT; i += stride) {
        float v = 0.0f;
        if (i < C_BI) { int r = i >> 8, j = i & 255; if (j < 250) v = W_in[r*250 + j]; }
        else if (i < C_BH) { int j = i - C_BI; if (j < 250) v = b_in[j]; }
        else if (i < C_WO) { int idx = i - C_BH; int l = idx >> 8, j = idx & 255; if (j < 250) v = b_h[l*250 + j]; }
        else { int idx = i - C_WO; int k = idx >> 2, o = idx & 3; if (k < 250) v = W_out[k*4 + o]; }
        cf[i] = v;
    }
}

// ---------------- fused PINN kernel ----------------
// 512 threads = 8 waves. Wave w owns col strip 32*w..32*w+31 for ALL 64 rows
// (2 row tiles -> 2 accumulators, 32 AGPR). One B load feeds 2 MFMAs; B traffic
// not duplicated across waves. Distance-4 register queues hide LDS/L2 latency.
__launch_bounds__(512, 4)
__global__ void pinn_mfma(const float* __restrict__ xg, const float* __restrict__ yg,
                          const float* __restrict__ tg, const void* __restrict__ wsv,
                          const float* __restrict__ b_out, const float* __restrict__ act,
                          float* __restrict__ out, int N)
{
    __shared__ _Float16 Ah[ROWS * PSTR];
    __shared__ float zo[PTS][28];

    const _Float16* __restrict__ wt = (const _Float16*)wsv;
    const float* __restrict__ cf = (const float*)((const char*)wsv + (size_t)WT_ELEMS * 2);

    const int tid  = threadIdx.x;
    const int lane = tid & 63;
    const int w    = tid >> 6;        // wave id: col strip 32*w
    const int lo5  = lane & 31;
    const int hi5  = lane >> 5;
    const int n0   = 32*w + lo5;      // this lane's output neuron (B row)

    // ---------- input layer jet: 512 threads, halves split the 8 points ----------
    {
        int j   = tid & 255;          // neuron
        int hf  = tid >> 8;           // 0: points 0-3, 1: points 4-7
        float wi0 = cf[C_WI + j], wi1 = cf[C_WI + 256 + j], wi2 = cf[C_WI + 512 + j];
        float biv = cf[C_BI + j];
        float c0 = 10.0f * act[0];
        #pragma unroll
        for (int p4 = 0; p4 < 4; ++p4) {
            int p  = 4*hf + p4;
            int gp = blockIdx.x * PTS + p;
            gp = gp < N ? gp : N - 1;
            float px = xg[gp], py = yg[gp], pt = tg[gp];
            float z = px*wi0 + py*wi1 + pt*wi2 + biv;
            float y = fast_tanh(c0 * z);
            float s = 1.0f - y*y;
            float cs = c0 * s;
            float m2 = -2.0f * c0 * cs * y;
            float o[8];
            o[0] = y;           o[1] = cs*wi0;      o[2] = cs*wi1;      o[3] = cs*wi2;
            o[4] = m2*wi0*wi0;  o[5] = m2*wi1*wi1;  o[6] = m2*wi0*wi1;  o[7] = 0.0f;
            #pragma unroll
            for (int c = 0; c < 8; ++c)
                Ah[arow(p, c)*PSTR + j] = (_Float16)o[c];
        }
    }

    // ---------- hidden layers ----------
    for (int L = 0; L < NLAYER; ++L) {
        float cc = 10.0f * act[L + 1];
        const _Float16* __restrict__ ph = wt + ((size_t)L << 16) + (size_t)n0 * 256 + 8*hi5;

        half8 Bq[4], A0q[4], A1q[4];
        #pragma unroll
        for (int i = 0; i < 4; ++i)                   // B preload before barrier (read-only)
            Bq[i] = *(const half8*)(ph + 16*i);

        float16v m0 = zero16(), m1 = zero16();

        __syncthreads();                              // A plane stable

        const int abase = lo5 * PSTR + 8*hi5;
        #pragma unroll
        for (int i = 0; i < 4; ++i) {
            A0q[i] = *(const half8*)&Ah[abase + 16*i];
            A1q[i] = *(const half8*)&Ah[abase + 32*PSTR + 16*i];
        }

        #pragma unroll
        for (int s = 0; s < 16; ++s) {
            half8 b  = Bq[s & 3];
            half8 a0 = A0q[s & 3];
            half8 a1 = A1q[s & 3];
            if (s < 12) {                             // refill distance-4 queues
                Bq[s & 3]  = *(const half8*)(ph + 16*(s + 4));
                A0q[s & 3] = *(const half8*)&Ah[abase + 16*(s + 4)];
                A1q[s & 3] = *(const half8*)&Ah[abase + 32*PSTR + 16*(s + 4)];
            }
            m0 = MFMA16(a0, b, m0);
            m1 = MFMA16(a1, b, m1);
        }

        __syncthreads();                              // all reads done before overwrite

        float bb = cf[C_BH + (L << 8) + n0];          // hidden bias (per output neuron)

        // ---- epilogue: shuffle-free, divergence-free; 2 row tiles x 2 points ----
        #pragma unroll
        for (int rt = 0; rt < 2; ++rt) {
            float16v mv = rt ? m1 : m0;
            #pragma unroll
            for (int pp = 0; pp < 2; ++pp) {
                float z   = mv[8*pp+0] + bb;
                float zx  = mv[8*pp+1];
                float zy  = mv[8*pp+2];
                float zt  = mv[8*pp+3];
                float zxx = mv[8*pp+4];
                float zyy = mv[8*pp+5];
                float zxy = mv[8*pp+6];
                float y   = fast_tanh(cc * z);
                float sh  = 1.0f - y*y;
                float cs  = cc * sh;
                float m2c = -2.0f * cc * cs * y;
                int r0 = (32*rt + 16*pp + 4*hi5) * PSTR + n0;   // quad 2pp rows (ch0-3)
                Ah[r0 + 0*PSTR] = (_Float16)y;
                Ah[r0 + 1*PSTR] = (_Float16)(cs*zx);
                Ah[r0 + 2*PSTR] = (_Float16)(cs*zy);
                Ah[r0 + 3*PSTR] = (_Float16)(cs*zt);
                int r1 = r0 + 8*PSTR;                            // quad 2pp+1 rows (ch4-7)
                Ah[r1 + 0*PSTR] = (_Float16)(cs*zxx + m2c*zx*zx);
                Ah[r1 + 1*PSTR] = (_Float16)(cs*zyy + m2c*zy*zy);
                Ah[r1 + 2*PSTR] = (_Float16)(cs*zxy + m2c*zx*zy);
                Ah[r1 + 3*PSTR] = (_Float16)0.0f;
            }
        }
    }

    // ---------- output layer: 28 dots per point ----------
    __syncthreads();
    if (tid < PTS * 28) {
        int p = tid / 28, idx = tid % 28;
        int c = idx >> 2, o = idx & 3;
        const _Float16* rh = &Ah[arow(p, c) * PSTR];
        float s = 0.0f;
        for (int k = 0; k < HP; ++k)
            s += (float)rh[k] * cf[C_WO + 4*k + o];
        zo[p][idx] = s;
    }
    __syncthreads();

    // ---------- heads + PDE residuals ----------
    if (tid < PTS) {
        int gp = blockIdx.x * PTS + tid;
        if (gp < N) {
            float zc[7][4];
            #pragma unroll
            for (int c = 0; c < 7; ++c)
                #pragma unroll
                for (int o = 0; o < 4; ++o)
                    zc[c][o] = zo[tid][c*4 + o] + (c == 0 ? b_out[o] : 0.0f);

            float u  = zc[0][0], vv = zc[0][1];
            float u_x = zc[1][0], u_y = zc[2][0], u_t = zc[3][0];
            float u_xx = zc[4][0], u_yy = zc[5][0];
            float v_x = zc[1][1], v_y = zc[2][1], v_t = zc[3][1];
            float v_xx = zc[4][1], v_yy = zc[5][1];

            float ep  = expf(zc[0][2]);
            float p_x = ep * zc[1][2], p_y = ep * zc[2][2];

            float a   = 1.0f / (1.0f + expf(-zc[0][3]));
            float sp  = a * (1.0f - a);
            float spp = sp * (1.0f - 2.0f*a);
            float z1a = zc[1][3], z2a = zc[2][3];
            float a_x = sp * z1a, a_y = sp * z2a, a_t = sp * zc[3][3];
            float a_xx = spp*z1a*z1a + sp*zc[4][3];
            float a_yy = spp*z2a*z2a + sp*zc[5][3];
            float a_xy = spp*z1a*z2a + sp*zc[6][3];

            float mu_x = -9.0f*a_x, mu_y = -9.0f*a_y;
            float mu   = 10.0f - 9.0f*a;
            float rr   = 1.0f - 0.9f*a;
            float g  = sqrtf(a_x*a_x + a_y*a_y + 2.220446049250313e-16f);
            float g3 = g*g*g;
            float curv = -((a_xx + a_yy)/g
                         - (a_x*a_x*a_xx + a_y*a_y*a_yy + 2.0f*a_x*a_y*a_xy)/g3);
            float one_Re   = mu   * 0.002f;
            float one_Re_x = mu_x * 0.002f;
            float one_Re_y = mu_y * 0.002f;

            float PDE_m = u_x + v_y;
            float PDE_a = a_t + u*a_x + vv*a_y;
            float PDE_u = (u_t + u*u_x + vv*u_y)*rr + p_x - 0.049f*curv*a_x
                        - one_Re*(u_xx + u_yy) - 2.0f*one_Re_x*u_x - one_Re_y*(u_y + v_x);
            float PDE_v = (v_t + u*v_x + vv*v_y)*rr + p_y - 0.049f*curv*a_y
                        - one_Re*(v_xx + v_yy) - rr*0.49f
                        - 2.0f*one_Re_y*v_y - one_Re_x*(u_y + v_x);

            out[0*N + gp] = PDE_m;
            out[1*N + gp] = PDE_u;
            out[2*N + gp] = PDE_v;
            out[3*N + gp] = PDE_a;
        }
    }
}

extern "C" void kernel_launch(void* const* d_in, const int* in_sizes, int n_in,
                              void* d_out, int out_size, void* d_ws, size_t ws_size,
                              hipStream_t stream)
{
    const float* x     = (const float*)d_in[0];
    const float* y     = (const float*)d_in[1];
    const float* t     = (const float*)d_in[2];
    const float* W_in  = (const float*)d_in[3];
    const float* b_in  = (const float*)d_in[4];
    const float* W_h   = (const float*)d_in[5];
    const float* b_h   = (const float*)d_in[6];
    const float* W_out = (const float*)d_in[7];
    const float* b_out = (const float*)d_in[8];
    const float* act   = (const float*)d_in[9];
    float* out = (float*)d_out;
    int N = in_sizes[0];

    hipLaunchKernelGGL(prep_kernel, dim3(512), dim3(256), 0, stream,
                       W_in, b_in, W_h, b_h, W_out, d_ws);
    int nb = (N + PTS - 1) / PTS;
    hipLaunchKernelGGL(pinn_mfma, dim3(nb), dim3(512), 0, stream,
                       x, y, t, d_ws, b_out, act, out, N);
}

// Round 13
// 313.704 us; speedup vs baseline: 2.4997x; 1.4581x over previous
//
#include <hip/hip_runtime.h>
#include <math.h>
#include <stdint.h>

#define HP 256
#define PTS 16                // points per workgroup
#define ROWS 128              // 16 points x 8 channels (ch7 dummy)
#define PSTR 264              // halves per A row (dw-stride 132 == 4 mod 32 -> 0-conflict, measured)
#define NLAYER 6
#define WT_ELEMS (6*256*256)  // fp16 weights, wave-packed

typedef _Float16 half8 __attribute__((ext_vector_type(8)));
typedef float  float16v __attribute__((ext_vector_type(16)));

// f32 extras section (float offsets; section starts at byte WT_ELEMS*2)
#define C_WI 0                // [3][256]
#define C_BI 768              // [256]
#define C_BH 1024             // [6][256]
#define C_WO 2560             // [256][4]
#define C_TOT 3584

__device__ __forceinline__ float fast_tanh(float x) {
    float e = __expf(2.0f * x);
    return 1.0f - __fdividef(2.0f, e + 1.0f);
}

__device__ __forceinline__ float16v zero16() {
    float16v z;
    #pragma unroll
    for (int i = 0; i < 16; ++i) z[i] = 0.0f;
    return z;
}

// A-row for (point P in 0..15, channel c in 0..7). Permuted so that in the
// 32x32 MFMA C-layout (row=(reg&3)+8*(reg>>2)+4*hi5) each lane's reg quads
// 2pp / 2pp+1 hold ch0-3 / ch4-7 of point 4*(P>>2)+2pp+hi5 -> shuffle-free epilogue.
__device__ __forceinline__ int arow(int P, int c) {
    return 32*(P >> 2) + 16*((P >> 1) & 1) + 4*(P & 1) + 8*(c >> 2) + (c & 3);
}

#define MFMA16(A,B,Cc) __builtin_amdgcn_mfma_f32_32x32x16_f16((A),(B),(Cc),0,0,0)

// ---------------- prep: pack weights wave-contiguous ----------------
// wq[L][s][strip][lane][j]: lane=(hi5<<5)|lo5 needs B[n=32*strip+lo5][k=16*s+8*hi5+j].
// One wave k-step load = contiguous 1 KB (perfectly coalesced dwordx4).
__global__ void prep_kernel(const float* __restrict__ W_in, const float* __restrict__ b_in,
                            const float* __restrict__ W_h,  const float* __restrict__ b_h,
                            const float* __restrict__ W_out, void* __restrict__ wsv)
{
    _Float16* wt = (_Float16*)wsv;
    float* cf = (float*)((char*)wsv + (size_t)WT_ELEMS * 2);

    int i0 = blockIdx.x * blockDim.x + threadIdx.x;
    int stride = gridDim.x * blockDim.x;
    for (int i = i0; i < WT_ELEMS; i += stride) {
        int j    = i & 7;
        int lane = (i >> 3) & 63;
        int st   = (i >> 9) & 7;
        int s    = (i >> 12) & 15;
        int L    = i >> 16;
        int lo5 = lane & 31, hi5 = lane >> 5;
        int n = 32*st + lo5;
        int k = 16*s + 8*hi5 + j;
        wt[i] = (_Float16)((n < 250 && k < 250) ? W_h[(L*250 + k)*250 + n] : 0.0f);
    }
    for (int i = i0; i < C_TOT; i += stride) {
        float v = 0.0f;
        if (i < C_BI) { int r = i >> 8, j = i & 255; if (j < 250) v = W_in[r*250 + j]; }
        else if (i < C_BH) { int j = i - C_BI; if (j < 250) v = b_in[j]; }
        else if (i < C_WO) { int idx = i - C_BH; int l = idx >> 8, j = idx & 255; if (j < 250) v = b_h[l*250 + j]; }
        else { int idx = i - C_WO; int k = idx >> 2, o = idx & 3; if (k < 250) v = W_out[k*4 + o]; }
        cf[i] = v;
    }
}

// ---------------- fused PINN kernel ----------------
// 512 threads = 8 waves. Wave w owns col strip 32*w..+31 for ALL 128 rows
// (4 row tiles -> 4 accumulators, 64 AGPR). One coalesced 1KB B load per k-step
// feeds 4 MFMAs. Weights streamed once per 16 points (half of rd12's traffic).
__launch_bounds__(512, 4)
__global__ void pinn_mfma(const float* __restrict__ xg, const float* __restrict__ yg,
                          const float* __restrict__ tg, const void* __restrict__ wsv,
                          const float* __restrict__ b_out, const float* __restrict__ act,
                          float* __restrict__ out, int N)
{
    __shared__ _Float16 Ah[ROWS * PSTR];
    __shared__ float zo[PTS][28];

    const _Float16* __restrict__ wt = (const _Float16*)wsv;
    const float* __restrict__ cf = (const float*)((const char*)wsv + (size_t)WT_ELEMS * 2);

    const int tid  = threadIdx.x;
    const int lane = tid & 63;
    const int w    = tid >> 6;        // wave id: col strip 32*w
    const int lo5  = lane & 31;
    const int hi5  = lane >> 5;
    const int n0   = 32*w + lo5;      // this lane's output neuron

    // ---------- input layer jet: halves of the block split the 16 points ----------
    {
        int j   = tid & 255;          // neuron
        int hf  = tid >> 8;           // 0: points 0-7, 1: points 8-15
        float wi0 = cf[C_WI + j], wi1 = cf[C_WI + 256 + j], wi2 = cf[C_WI + 512 + j];
        float biv = cf[C_BI + j];
        float c0 = 10.0f * act[0];
        #pragma unroll
        for (int p8 = 0; p8 < 8; ++p8) {
            int p  = 8*hf + p8;
            int gp = blockIdx.x * PTS + p;
            gp = gp < N ? gp : N - 1;
            float px = xg[gp], py = yg[gp], pt = tg[gp];
            float z = px*wi0 + py*wi1 + pt*wi2 + biv;
            float y = fast_tanh(c0 * z);
            float s = 1.0f - y*y;
            float cs = c0 * s;
            float m2 = -2.0f * c0 * cs * y;
            float o[8];
            o[0] = y;           o[1] = cs*wi0;      o[2] = cs*wi1;      o[3] = cs*wi2;
            o[4] = m2*wi0*wi0;  o[5] = m2*wi1*wi1;  o[6] = m2*wi0*wi1;  o[7] = 0.0f;
            #pragma unroll
            for (int c = 0; c < 8; ++c)
                Ah[arow(p, c)*PSTR + j] = (_Float16)o[c];
        }
    }

    // ---------- hidden layers ----------
    for (int L = 0; L < NLAYER; ++L) {
        float cc = 10.0f * act[L + 1];
        // wave-packed weights: step s at ph + 4096*s (1KB contiguous per wave)
        const _Float16* __restrict__ ph = wt + ((size_t)L << 16) + ((size_t)w << 9)
                                             + (size_t)lane * 8;

        half8 Bq[4];
        #pragma unroll
        for (int i = 0; i < 4; ++i)                   // B preload before barrier (read-only)
            Bq[i] = *(const half8*)(ph + 4096*i);

        float16v m[4];
        #pragma unroll
        for (int rt = 0; rt < 4; ++rt) m[rt] = zero16();

        __syncthreads();                              // A plane stable

        const int abase = lo5 * PSTR + 8*hi5;
        half8 a0[4], a1[4];
        #pragma unroll
        for (int rt = 0; rt < 4; ++rt) {
            a0[rt] = *(const half8*)&Ah[abase + 32*rt*PSTR];
            a1[rt] = *(const half8*)&Ah[abase + 32*rt*PSTR + 16];
        }

        #pragma unroll
        for (int s = 0; s < 16; ++s) {
            half8 b = Bq[s & 3];
            if (s < 12)                               // refill distance-4 B queue
                Bq[s & 3] = *(const half8*)(ph + 4096*(s + 4));
            half8 cur[4];
            #pragma unroll
            for (int rt = 0; rt < 4; ++rt) { cur[rt] = a0[rt]; a0[rt] = a1[rt]; }
            if (s < 14) {
                #pragma unroll
                for (int rt = 0; rt < 4; ++rt)        // refill distance-2 A queue
                    a1[rt] = *(const half8*)&Ah[abase + 32*rt*PSTR + 16*(s + 2)];
            }
            #pragma unroll
            for (int rt = 0; rt < 4; ++rt)
                m[rt] = MFMA16(cur[rt], b, m[rt]);
        }

        __syncthreads();                              // all reads done before overwrite

        float bb = cf[C_BH + (L << 8) + n0];          // hidden bias (per output neuron)

        // ---- epilogue: shuffle-free, divergence-free; 4 row tiles x 2 points ----
        #pragma unroll
        for (int rt = 0; rt < 4; ++rt) {
            float16v mv = m[rt];
            #pragma unroll
            for (int pp = 0; pp < 2; ++pp) {
                float z   = mv[8*pp+0] + bb;
                float zx  = mv[8*pp+1];
                float zy  = mv[8*pp+2];
                float zt  = mv[8*pp+3];
                float zxx = mv[8*pp+4];
                float zyy = mv[8*pp+5];
                float zxy = mv[8*pp+6];
                float y   = fast_tanh(cc * z);
                float sh  = 1.0f - y*y;
                float cs  = cc * sh;
                float m2c = -2.0f * cc * cs * y;
                int r0 = (32*rt + 16*pp + 4*hi5) * PSTR + n0;   // quad 2pp rows (ch0-3)
                Ah[r0 + 0*PSTR] = (_Float16)y;
                Ah[r0 + 1*PSTR] = (_Float16)(cs*zx);
                Ah[r0 + 2*PSTR] = (_Float16)(cs*zy);
                Ah[r0 + 3*PSTR] = (_Float16)(cs*zt);
                int r1 = r0 + 8*PSTR;                            // quad 2pp+1 rows (ch4-7)
                Ah[r1 + 0*PSTR] = (_Float16)(cs*zxx + m2c*zx*zx);
                Ah[r1 + 1*PSTR] = (_Float16)(cs*zyy + m2c*zy*zy);
                Ah[r1 + 2*PSTR] = (_Float16)(cs*zxy + m2c*zx*zy);
                Ah[r1 + 3*PSTR] = (_Float16)0.0f;
            }
        }
    }

    // ---------- output layer: 28 dots per point ----------
    __syncthreads();
    if (tid < PTS * 28) {
        int p = tid / 28, idx = tid % 28;
        int c = idx >> 2, o = idx & 3;
        const _Float16* rh = &Ah[arow(p, c) * PSTR];
        float s = 0.0f;
        for (int k = 0; k < HP; ++k)
            s += (float)rh[k] * cf[C_WO + 4*k + o];
        zo[p][idx] = s;
    }
    __syncthreads();

    // ---------- heads + PDE residuals ----------
    if (tid < PTS) {
        int gp = blockIdx.x * PTS + tid;
        if (gp < N) {
            float zc[7][4];
            #pragma unroll
            for (int c = 0; c < 7; ++c)
                #pragma unroll
                for (int o = 0; o < 4; ++o)
                    zc[c][o] = zo[tid][c*4 + o] + (c == 0 ? b_out[o] : 0.0f);

            float u  = zc[0][0], vv = zc[0][1];
            float u_x = zc[1][0], u_y = zc[2][0], u_t = zc[3][0];
            float u_xx = zc[4][0], u_yy = zc[5][0];
            float v_x = zc[1][1], v_y = zc[2][1], v_t = zc[3][1];
            float v_xx = zc[4][1], v_yy = zc[5][1];

            float ep  = expf(zc[0][2]);
            float p_x = ep * zc[1][2], p_y = ep * zc[2][2];

            float a   = 1.0f / (1.0f + expf(-zc[0][3]));
            float sp  = a * (1.0f - a);
            float spp = sp * (1.0f - 2.0f*a);
            float z1a = zc[1][3], z2a = zc[2][3];
            float a_x = sp * z1a, a_y = sp * z2a, a_t = sp * zc[3][3];
            float a_xx = spp*z1a*z1a + sp*zc[4][3];
            float a_yy = spp*z2a*z2a + sp*zc[5][3];
            float a_xy = spp*z1a*z2a + sp*zc[6][3];

            float mu_x = -9.0f*a_x, mu_y = -9.0f*a_y;
            float mu   = 10.0f - 9.0f*a;
            float rr   = 1.0f - 0.9f*a;
            float g  = sqrtf(a_x*a_x + a_y*a_y + 2.220446049250313e-16f);
            float g3 = g*g*g;
            float curv = -((a_xx + a_yy)/g
                         - (a_x*a_x*a_xx + a_y*a_y*a_yy + 2.0f*a_x*a_y*a_xy)/g3);
            float one_Re   = mu   * 0.002f;
            float one_Re_x = mu_x * 0.002f;
            float one_Re_y = mu_y * 0.002f;

            float PDE_m = u_x + v_y;
            float PDE_a = a_t + u*a_x + vv*a_y;
            float PDE_u = (u_t + u*u_x + vv*u_y)*rr + p_x - 0.049f*curv*a_x
                        - one_Re*(u_xx + u_yy) - 2.0f*one_Re_x*u_x - one_Re_y*(u_y + v_x);
            float PDE_v = (v_t + u*v_x + vv*v_y)*rr + p_y - 0.049f*curv*a_y
                        - one_Re*(v_xx + v_yy) - rr*0.49f
                        - 2.0f*one_Re_y*v_y - one_Re_x*(u_y + v_x);

            out[0*N + gp] = PDE_m;
            out[1*N + gp] = PDE_u;
            out[2*N + gp] = PDE_v;
            out[3*N + gp] = PDE_a;
        }
    }
}

extern "C" void kernel_launch(void* const* d_in, const int* in_sizes, int n_in,
                              void* d_out, int out_size, void* d_ws, size_t ws_size,
                              hipStream_t stream)
{
    const float* x     = (const float*)d_in[0];
    const float* y     = (const float*)d_in[1];
    const float* t     = (const float*)d_in[2];
    const float* W_in  = (const float*)d_in[3];
    const float* b_in  = (const float*)d_in[4];
    const float* W_h   = (const float*)d_in[5];
    const float* b_h   = (const float*)d_in[6];
    const float* W_out = (const float*)d_in[7];
    const float* b_out = (const float*)d_in[8];
    const float* act   = (const float*)d_in[9];
    float* out = (float*)d_out;
    int N = in_sizes[0];

    hipLaunchKernelGGL(prep_kernel, dim3(512), dim3(256), 0, stream,
                       W_in, b_in, W_h, b_h, W_out, d_ws);
    int nb = (N + PTS - 1) / PTS;
    hipLaunchKernelGGL(pinn_mfma, dim3(nb), dim3(512), 0, stream,
                       x, y, t, d_ws, b_out, act, out, N);
}